// Round 7
// baseline (1732.610 us; speedup 1.0000x reference)
//
#include <hip/hip_runtime.h>
#include <math.h>

#define HID 64
#define LR_ATT 0.2f
#define LR_ACT 0.01f

// float atomic max via int reinterpretation (valid when mixing pos/neg, init -inf)
__device__ inline void atomicMaxF(float* addr, float val) {
    if (val >= 0.f) atomicMax((int*)addr, __float_as_int(val));
    else            atomicMin((unsigned int*)addr, (unsigned int)__float_as_int(val));
}

// h = hin @ W  (K x 64), al_s = h.a_src, al_d = h.a_dst; zero-init agg/denom, m=-inf.
// One wave per node (grid-stride). Lane c owns output channel c.
template<int K>
__global__ __launch_bounds__(256) void gemm_att_kernel(
    const float* __restrict__ hin, const float* __restrict__ W,
    const float* __restrict__ a_src, const float* __restrict__ a_dst,
    float* __restrict__ hout, float* __restrict__ al_s, float* __restrict__ al_d,
    float* __restrict__ agg, float* __restrict__ denom, float* __restrict__ mx,
    int n_nodes)
{
    __shared__ float Wl[K * HID];
    for (int i = threadIdx.x; i < K * HID; i += blockDim.x) Wl[i] = W[i];
    __syncthreads();

    const int lane = threadIdx.x & 63;
    const int wib  = threadIdx.x >> 6;
    const int wpb  = blockDim.x >> 6;
    int wid = blockIdx.x * wpb + wib;
    int nw  = gridDim.x * wpb;

    const float as = a_src[lane];
    const float ad = a_dst[lane];

    for (int nn = wid; nn < n_nodes; nn += nw) {
        const float* xr = hin + (size_t)nn * K;
        float acc = 0.f;
        #pragma unroll 8
        for (int k = 0; k < K; ++k)
            acc = fmaf(xr[k], Wl[k * HID + lane], acc);

        hout[(size_t)nn * HID + lane] = acc;
        agg [(size_t)nn * HID + lane] = 0.f;

        float ps = acc * as, pd = acc * ad;
        #pragma unroll
        for (int off = 32; off; off >>= 1) {
            ps += __shfl_xor(ps, off);
            pd += __shfl_xor(pd, off);
        }
        if (lane == 0) {
            al_s[nn]  = ps;
            al_d[nn]  = pd;
            denom[nn] = 0.f;
            mx[nn]    = __int_as_float(0xff800000); // -inf
        }
    }
}

// Pass 1: segment max of edge logits over dst (incl. self-loops at idx >= E)
__global__ __launch_bounds__(256) void edge_max_kernel(
    const int* __restrict__ src, const int* __restrict__ dst,
    const float* __restrict__ al_s, const float* __restrict__ al_d,
    float* __restrict__ mx, int E, int n_nodes)
{
    int idx    = blockIdx.x * blockDim.x + threadIdx.x;
    int total  = E + n_nodes;
    int stride = gridDim.x * blockDim.x;
    for (; idx < total; idx += stride) {
        int s, d;
        if (idx < E) { s = src[idx]; d = dst[idx]; }
        else         { s = idx - E; d = s; }
        float e = al_s[s] + al_d[d];
        e = (e > 0.f) ? e : LR_ATT * e;
        atomicMaxF(mx + d, e);
    }
}

// Pass 2: ex = exp(e - m[dst]); denom[dst] += ex; agg[dst][c] += ex * h[src][c]
// One wave per edge (grid-stride); lane = channel.
__global__ __launch_bounds__(256) void edge_agg_kernel(
    const int* __restrict__ src, const int* __restrict__ dst,
    const float* __restrict__ al_s, const float* __restrict__ al_d,
    const float* __restrict__ h, const float* __restrict__ mx,
    float* __restrict__ agg, float* __restrict__ denom, int E, int n_nodes)
{
    const int lane = threadIdx.x & 63;
    int wid = (blockIdx.x * blockDim.x + threadIdx.x) >> 6;
    int nw  = (gridDim.x * blockDim.x) >> 6;
    int total = E + n_nodes;
    for (int idx = wid; idx < total; idx += nw) {
        int s, d;
        if (idx < E) { s = src[idx]; d = dst[idx]; }
        else         { s = idx - E; d = s; }
        float e = al_s[s] + al_d[d];
        e = (e > 0.f) ? e : LR_ATT * e;
        float ex = expf(e - mx[d]);
        if (lane == 0) unsafeAtomicAdd(denom + d, ex);
        float hv = h[(size_t)s * HID + lane];
        unsafeAtomicAdd(agg + (size_t)d * HID + lane, ex * hv);
    }
}

// out = leaky_relu(agg/denom + b, 0.01)
__global__ __launch_bounds__(256) void finalize_kernel(
    const float* __restrict__ agg, const float* __restrict__ denom,
    const float* __restrict__ b, float* __restrict__ hout, int n_nodes)
{
    int t      = blockIdx.x * blockDim.x + threadIdx.x;
    int total  = n_nodes * HID;
    int stride = gridDim.x * blockDim.x;
    for (; t < total; t += stride) {
        int nn = t >> 6;
        int c  = t & 63;
        float v = agg[t] / denom[nn] + b[c];
        v = (v > 0.f) ? v : LR_ACT * v;
        hout[t] = v;
    }
}

// out[n] = dot(h[n], W_out) + b_out   (wave per node, shuffle reduce)
__global__ __launch_bounds__(256) void head_kernel(
    const float* __restrict__ h, const float* __restrict__ Wout,
    const float* __restrict__ bout, float* __restrict__ out, int n_nodes)
{
    const int lane = threadIdx.x & 63;
    int wid = (blockIdx.x * blockDim.x + threadIdx.x) >> 6;
    int nw  = (gridDim.x * blockDim.x) >> 6;
    const float w  = Wout[lane];
    const float bb = bout[0];
    for (int nn = wid; nn < n_nodes; nn += nw) {
        float v = h[(size_t)nn * HID + lane] * w;
        #pragma unroll
        for (int off = 32; off; off >>= 1) v += __shfl_xor(v, off);
        if (lane == 0) out[nn] = v + bb;
    }
}

extern "C" void kernel_launch(void* const* d_in, const int* in_sizes, int n_in,
                              void* d_out, int out_size, void* d_ws, size_t ws_size,
                              hipStream_t stream)
{
    const float* x      = (const float*)d_in[0];
    const int*   ei     = (const int*)  d_in[1];
    const float* W1     = (const float*)d_in[2];
    const float* a_src1 = (const float*)d_in[3];
    const float* a_dst1 = (const float*)d_in[4];
    const float* b1     = (const float*)d_in[5];
    const float* W2     = (const float*)d_in[6];
    const float* a_src2 = (const float*)d_in[7];
    const float* a_dst2 = (const float*)d_in[8];
    const float* b2     = (const float*)d_in[9];
    const float* W3     = (const float*)d_in[10];
    const float* a_src3 = (const float*)d_in[11];
    const float* a_dst3 = (const float*)d_in[12];
    const float* b3     = (const float*)d_in[13];
    const float* W_out  = (const float*)d_in[14];
    const float* b_out  = (const float*)d_in[15];
    float* out = (float*)d_out;

    const int n = out_size;           // 50000 nodes
    const int E = in_sizes[1] / 2;    // 1.6M edges

    const int* src = ei;
    const int* dst = ei + E;

    float* ws    = (float*)d_ws;
    float* hA    = ws;                       // n*64
    float* hB    = hA + (size_t)n * HID;     // n*64
    float* agg   = hB + (size_t)n * HID;     // n*64
    float* al_s  = agg + (size_t)n * HID;    // n
    float* al_d  = al_s + n;                 // n
    float* mx    = al_d + n;                 // n
    float* denom = mx + n;                   // n

    dim3 blk(256);
    const int gemm_grid  = 1024;
    int edge_grid1 = (E + n + 255) / 256; if (edge_grid1 > 8192) edge_grid1 = 8192;
    const int edge_grid2 = 2048;
    const int fin_grid   = (n * HID + 255) / 256;
    const int head_grid  = 1024;

    // ---- layer 1 (K = 128) ----
    gemm_att_kernel<128><<<gemm_grid, blk, 0, stream>>>(x, W1, a_src1, a_dst1,
        hA, al_s, al_d, agg, denom, mx, n);
    edge_max_kernel<<<edge_grid1, blk, 0, stream>>>(src, dst, al_s, al_d, mx, E, n);
    edge_agg_kernel<<<edge_grid2, blk, 0, stream>>>(src, dst, al_s, al_d, hA, mx, agg, denom, E, n);
    finalize_kernel<<<fin_grid, blk, 0, stream>>>(agg, denom, b1, hB, n);

    // ---- layer 2 (K = 64) ----
    gemm_att_kernel<64><<<gemm_grid, blk, 0, stream>>>(hB, W2, a_src2, a_dst2,
        hA, al_s, al_d, agg, denom, mx, n);
    edge_max_kernel<<<edge_grid1, blk, 0, stream>>>(src, dst, al_s, al_d, mx, E, n);
    edge_agg_kernel<<<edge_grid2, blk, 0, stream>>>(src, dst, al_s, al_d, hA, mx, agg, denom, E, n);
    finalize_kernel<<<fin_grid, blk, 0, stream>>>(agg, denom, b2, hB, n);

    // ---- layer 3 (K = 64) ----
    gemm_att_kernel<64><<<gemm_grid, blk, 0, stream>>>(hB, W3, a_src3, a_dst3,
        hA, al_s, al_d, agg, denom, mx, n);
    edge_max_kernel<<<edge_grid1, blk, 0, stream>>>(src, dst, al_s, al_d, mx, E, n);
    edge_agg_kernel<<<edge_grid2, blk, 0, stream>>>(src, dst, al_s, al_d, hA, mx, agg, denom, E, n);
    finalize_kernel<<<fin_grid, blk, 0, stream>>>(agg, denom, b3, hB, n);

    // ---- output head ----
    head_kernel<<<head_grid, blk, 0, stream>>>(hB, W_out, b_out, out, n);
}

// Round 8
// 921.727 us; speedup vs baseline: 1.8797x; 1.8797x over previous
//
#include <hip/hip_runtime.h>
#include <math.h>

#define HID 64
#define LR_ATT 0.2f
#define LR_ACT 0.01f
#define SCAN_NT 1024

// ---------------- CSR build (once per call; graph shared by all 3 layers) ----------------

__global__ __launch_bounds__(256) void zero_counts_kernel(int* __restrict__ counts, int n)
{
    int i = blockIdx.x * blockDim.x + threadIdx.x;
    int stride = gridDim.x * blockDim.x;
    for (; i < n; i += stride) counts[i] = 0;
}

__global__ __launch_bounds__(256) void count_kernel(
    const int* __restrict__ dst, int* __restrict__ counts, int E)
{
    int i = blockIdx.x * blockDim.x + threadIdx.x;
    int stride = gridDim.x * blockDim.x;
    for (; i < E; i += stride) atomicAdd(&counts[dst[i]], 1);
}

// Single-block exclusive scan of counts[0..n) -> offsets[0..n], plus cursor copy.
__global__ __launch_bounds__(SCAN_NT) void scan_kernel(
    const int* __restrict__ counts, int* __restrict__ offsets,
    int* __restrict__ cursor, int n)
{
    __shared__ int sdata[SCAN_NT];
    const int t = threadIdx.x;
    const int C = (n + SCAN_NT - 1) / SCAN_NT;
    const int beg = t * C;
    const int end = min(n, beg + C);

    int local = 0;
    for (int i = beg; i < end; ++i) local += counts[i];
    sdata[t] = local;
    __syncthreads();
    // Hillis-Steele inclusive scan over SCAN_NT entries
    for (int off = 1; off < SCAN_NT; off <<= 1) {
        int v = (t >= off) ? sdata[t - off] : 0;
        __syncthreads();
        sdata[t] += v;
        __syncthreads();
    }
    int run = sdata[t] - local;  // exclusive base for this thread's chunk
    for (int i = beg; i < end; ++i) {
        offsets[i] = run;
        cursor[i]  = run;
        run += counts[i];
    }
    if (end == n && beg <= n) offsets[n] = run;  // total == E
}

__global__ __launch_bounds__(256) void scatter_kernel(
    const int* __restrict__ src, const int* __restrict__ dst,
    int* __restrict__ cursor, int* __restrict__ sorted_src, int E)
{
    int i = blockIdx.x * blockDim.x + threadIdx.x;
    int stride = gridDim.x * blockDim.x;
    for (; i < E; i += stride) {
        int d = dst[i];
        int pos = atomicAdd(&cursor[d], 1);
        sorted_src[pos] = src[i];
    }
}

// ---------------- per-layer kernels ----------------

// h = hin @ W  (K x 64), al_s = h.a_src, al_d = h.a_dst.
// One wave per node (grid-stride). Lane c owns output channel c.
template<int K>
__global__ __launch_bounds__(256) void gemm_att_kernel(
    const float* __restrict__ hin, const float* __restrict__ W,
    const float* __restrict__ a_src, const float* __restrict__ a_dst,
    float* __restrict__ hout, float* __restrict__ al_s, float* __restrict__ al_d,
    int n_nodes)
{
    __shared__ float Wl[K * HID];
    for (int i = threadIdx.x; i < K * HID; i += blockDim.x) Wl[i] = W[i];
    __syncthreads();

    const int lane = threadIdx.x & 63;
    const int wib  = threadIdx.x >> 6;
    const int wpb  = blockDim.x >> 6;
    int wid = blockIdx.x * wpb + wib;
    int nw  = gridDim.x * wpb;

    const float as = a_src[lane];
    const float ad = a_dst[lane];

    for (int nn = wid; nn < n_nodes; nn += nw) {
        const float* xr = hin + (size_t)nn * K;
        float acc = 0.f;
        #pragma unroll 8
        for (int k = 0; k < K; ++k)
            acc = fmaf(xr[k], Wl[k * HID + lane], acc);

        hout[(size_t)nn * HID + lane] = acc;

        float ps = acc * as, pd = acc * ad;
        #pragma unroll
        for (int off = 32; off; off >>= 1) {
            ps += __shfl_xor(ps, off);
            pd += __shfl_xor(pd, off);
        }
        if (lane == 0) {
            al_s[nn] = ps;
            al_d[nn] = pd;
        }
    }
}

// One wave per dst node: online softmax over CSR edges + implicit self-loop,
// register accumulation (lane = channel), fused divide+bias+leaky_relu.
// FUSE_HEAD: additionally fold the output head (dot with W_out + b_out -> out[d]).
template<bool FUSE_HEAD>
__global__ __launch_bounds__(256) void node_agg_kernel(
    const int* __restrict__ offsets, const int* __restrict__ sorted_src,
    const float* __restrict__ al_s, const float* __restrict__ al_d,
    const float* __restrict__ h, const float* __restrict__ b,
    float* __restrict__ hout,
    const float* __restrict__ Wout, const float* __restrict__ bout,
    float* __restrict__ out, int n_nodes)
{
    const int lane = threadIdx.x & 63;
    const int wib  = threadIdx.x >> 6;
    const int wpb  = blockDim.x >> 6;
    int wid = blockIdx.x * wpb + wib;
    int nw  = gridDim.x * wpb;

    const float bc = b[lane];
    const float wc = FUSE_HEAD ? Wout[lane] : 0.f;

    for (int d = wid; d < n_nodes; d += nw) {
        const float ald = al_d[d];
        // self-loop initializes the running softmax state
        float e0 = al_s[d] + ald;
        e0 = (e0 > 0.f) ? e0 : LR_ATT * e0;
        float m   = e0;
        float sum = 1.f;
        float acc = h[(size_t)d * HID + lane];

        const int k0 = offsets[d];
        const int k1 = offsets[d + 1];
        for (int k = k0; k < k1; ++k) {
            int s = sorted_src[k];                 // wave-uniform
            float e = al_s[s] + ald;
            e = (e > 0.f) ? e : LR_ATT * e;        // wave-uniform
            float hv = h[(size_t)s * HID + lane];  // coalesced 256B gather
            if (e > m) {                           // wave-uniform branch
                float r = __expf(m - e);
                acc = fmaf(acc, r, hv);
                sum = fmaf(sum, r, 1.f);
                m = e;
            } else {
                float ex = __expf(e - m);
                acc = fmaf(ex, hv, acc);
                sum += ex;
            }
        }

        float v = acc / sum + bc;
        v = (v > 0.f) ? v : LR_ACT * v;
        if (!FUSE_HEAD) {
            hout[(size_t)d * HID + lane] = v;
        } else {
            v *= wc;
            #pragma unroll
            for (int off = 32; off; off >>= 1) v += __shfl_xor(v, off);
            if (lane == 0) out[d] = v + bout[0];
        }
    }
}

extern "C" void kernel_launch(void* const* d_in, const int* in_sizes, int n_in,
                              void* d_out, int out_size, void* d_ws, size_t ws_size,
                              hipStream_t stream)
{
    const float* x      = (const float*)d_in[0];
    const int*   ei     = (const int*)  d_in[1];
    const float* W1     = (const float*)d_in[2];
    const float* a_src1 = (const float*)d_in[3];
    const float* a_dst1 = (const float*)d_in[4];
    const float* b1     = (const float*)d_in[5];
    const float* W2     = (const float*)d_in[6];
    const float* a_src2 = (const float*)d_in[7];
    const float* a_dst2 = (const float*)d_in[8];
    const float* b2     = (const float*)d_in[9];
    const float* W3     = (const float*)d_in[10];
    const float* a_src3 = (const float*)d_in[11];
    const float* a_dst3 = (const float*)d_in[12];
    const float* b3     = (const float*)d_in[13];
    const float* W_out  = (const float*)d_in[14];
    const float* b_out  = (const float*)d_in[15];
    float* out = (float*)d_out;

    const int n = out_size;           // 50000 nodes
    const int E = in_sizes[1] / 2;    // 1.6M edges

    const int* src = ei;
    const int* dst = ei + E;

    // workspace layout
    float* ws   = (float*)d_ws;
    float* hA   = ws;                        // n*64
    float* hB   = hA + (size_t)n * HID;      // n*64
    float* al_s = hB + (size_t)n * HID;      // n
    float* al_d = al_s + n;                  // n
    int* counts     = (int*)(al_d + n);      // n
    int* offsets    = counts + n;            // n+1
    int* cursor     = offsets + (n + 1);     // n
    int* sorted_src = cursor + n;            // E

    dim3 blk(256);
    const int gemm_grid = 1024;
    const int edge_grid = 4096;
    const int node_grid = (n + 3) / 4;       // 4 waves/block, 1 wave/node
    const int zero_grid = (n + 255) / 256;

    // ---- CSR build (graph is layer-invariant) ----
    zero_counts_kernel<<<zero_grid, blk, 0, stream>>>(counts, n);
    count_kernel<<<edge_grid, blk, 0, stream>>>(dst, counts, E);
    scan_kernel<<<1, SCAN_NT, 0, stream>>>(counts, offsets, cursor, n);
    scatter_kernel<<<edge_grid, blk, 0, stream>>>(src, dst, cursor, sorted_src, E);

    // ---- layer 1 (K = 128) ----
    gemm_att_kernel<128><<<gemm_grid, blk, 0, stream>>>(x, W1, a_src1, a_dst1,
        hA, al_s, al_d, n);
    node_agg_kernel<false><<<node_grid, blk, 0, stream>>>(offsets, sorted_src,
        al_s, al_d, hA, b1, hB, nullptr, nullptr, nullptr, n);

    // ---- layer 2 (K = 64) ----
    gemm_att_kernel<64><<<gemm_grid, blk, 0, stream>>>(hB, W2, a_src2, a_dst2,
        hA, al_s, al_d, n);
    node_agg_kernel<false><<<node_grid, blk, 0, stream>>>(offsets, sorted_src,
        al_s, al_d, hA, b2, hB, nullptr, nullptr, nullptr, n);

    // ---- layer 3 (K = 64) + fused output head ----
    gemm_att_kernel<64><<<gemm_grid, blk, 0, stream>>>(hB, W3, a_src3, a_dst3,
        hA, al_s, al_d, n);
    node_agg_kernel<true><<<node_grid, blk, 0, stream>>>(offsets, sorted_src,
        al_s, al_d, hA, b3, nullptr, W_out, b_out, out, n);
}

// Round 9
// 659.492 us; speedup vs baseline: 2.6272x; 1.3976x over previous
//
#include <hip/hip_runtime.h>
#include <math.h>

#define HID 64
#define LR_ATT 0.2f
#define LR_ACT 0.01f
#define SCAN_NT 1024

// ---------------- CSR build (once per call; graph shared by all 3 layers) ----------------

__global__ __launch_bounds__(256) void count_kernel(
    const int* __restrict__ dst, int* __restrict__ counts, int E)
{
    int i = blockIdx.x * blockDim.x + threadIdx.x;
    int stride = gridDim.x * blockDim.x;
    for (; i < E; i += stride) atomicAdd(&counts[dst[i]], 1);
}

// Single-block exclusive scan of counts[0..n) -> offsets[0..n], plus cursor copy.
__global__ __launch_bounds__(SCAN_NT) void scan_kernel(
    const int* __restrict__ counts, int* __restrict__ offsets,
    int* __restrict__ cursor, int n)
{
    __shared__ int sdata[SCAN_NT];
    const int t = threadIdx.x;
    const int C = (n + SCAN_NT - 1) / SCAN_NT;
    const int beg = t * C;
    const int end = min(n, beg + C);

    int local = 0;
    for (int i = beg; i < end; ++i) local += counts[i];
    sdata[t] = local;
    __syncthreads();
    // Hillis-Steele inclusive scan over SCAN_NT entries
    for (int off = 1; off < SCAN_NT; off <<= 1) {
        int v = (t >= off) ? sdata[t - off] : 0;
        __syncthreads();
        sdata[t] += v;
        __syncthreads();
    }
    int run = sdata[t] - local;  // exclusive base for this thread's chunk
    for (int i = beg; i < end; ++i) {
        offsets[i] = run;
        cursor[i]  = run;
        run += counts[i];
    }
    if (end == n && beg <= n) offsets[n] = run;  // total == E
}

__global__ __launch_bounds__(256) void scatter_kernel(
    const int* __restrict__ src, const int* __restrict__ dst,
    int* __restrict__ cursor, int* __restrict__ sorted_src, int E)
{
    int i = blockIdx.x * blockDim.x + threadIdx.x;
    int stride = gridDim.x * blockDim.x;
    for (; i < E; i += stride) {
        int d = dst[i];
        int pos = atomicAdd(&cursor[d], 1);
        sorted_src[pos] = src[i];
    }
}

// ---------------- per-layer kernels ----------------

// h = hin @ W  (K x 64), al_s = h.a_src, al_d = h.a_dst.
// One wave per node (grid-stride). Lane c owns output channel c.
template<int K>
__global__ __launch_bounds__(256) void gemm_att_kernel(
    const float* __restrict__ hin, const float* __restrict__ W,
    const float* __restrict__ a_src, const float* __restrict__ a_dst,
    float* __restrict__ hout, float* __restrict__ al_s, float* __restrict__ al_d,
    int n_nodes)
{
    __shared__ float Wl[K * HID];
    for (int i = threadIdx.x; i < K * HID; i += blockDim.x) Wl[i] = W[i];
    __syncthreads();

    const int lane = threadIdx.x & 63;
    const int wib  = threadIdx.x >> 6;
    const int wpb  = blockDim.x >> 6;
    int wid = blockIdx.x * wpb + wib;
    int nw  = gridDim.x * wpb;

    const float as = a_src[lane];
    const float ad = a_dst[lane];

    for (int nn = wid; nn < n_nodes; nn += nw) {
        const float* xr = hin + (size_t)nn * K;
        float acc = 0.f;
        #pragma unroll 8
        for (int k = 0; k < K; ++k)
            acc = fmaf(xr[k], Wl[k * HID + lane], acc);

        hout[(size_t)nn * HID + lane] = acc;

        float ps = acc * as, pd = acc * ad;
        #pragma unroll
        for (int off = 32; off; off >>= 1) {
            ps += __shfl_xor(ps, off);
            pd += __shfl_xor(pd, off);
        }
        if (lane == 0) {
            al_s[nn] = ps;
            al_d[nn] = pd;
        }
    }
}

// One wave per dst node. Phase 1: lane-parallel segment max (strided edges,
// shuffle reduce). Phase 2: branch-free weighted gather-accumulate with known
// max -> deep pipelining of the h[src] gathers. Fused divide+bias+leaky_relu.
// FUSE_HEAD: additionally fold the output head (dot with W_out + b_out).
template<bool FUSE_HEAD>
__global__ __launch_bounds__(256) void node_agg_kernel(
    const int* __restrict__ offsets, const int* __restrict__ sorted_src,
    const float* __restrict__ al_s, const float* __restrict__ al_d,
    const float* __restrict__ h, const float* __restrict__ b,
    float* __restrict__ hout,
    const float* __restrict__ Wout, const float* __restrict__ bout,
    float* __restrict__ out, int n_nodes)
{
    const int lane = threadIdx.x & 63;
    const int wib  = threadIdx.x >> 6;
    const int wpb  = blockDim.x >> 6;
    int wid = blockIdx.x * wpb + wib;
    int nw  = gridDim.x * wpb;

    const float bc = b[lane];
    const float wc = FUSE_HEAD ? Wout[lane] : 0.f;

    for (int d = wid; d < n_nodes; d += nw) {
        const float ald = al_d[d];
        float e0 = al_s[d] + ald;           // self-loop logit
        e0 = (e0 > 0.f) ? e0 : LR_ATT * e0;

        const int k0 = offsets[d];
        const int k1 = offsets[d + 1];

        // ---- phase 1: lane-parallel max over edge logits ----
        float lm = e0;
        for (int k = k0 + lane; k < k1; k += 64) {
            int s = sorted_src[k];
            float e = al_s[s] + ald;
            e = (e > 0.f) ? e : LR_ATT * e;
            lm = fmaxf(lm, e);
        }
        #pragma unroll
        for (int off = 32; off; off >>= 1)
            lm = fmaxf(lm, __shfl_xor(lm, off));
        const float m = lm;

        // ---- phase 2: branch-free accumulate (lane = channel) ----
        float ex0 = __expf(e0 - m);
        float sum = ex0;
        float acc = ex0 * h[(size_t)d * HID + lane];
        #pragma unroll 4
        for (int k = k0; k < k1; ++k) {
            int s = sorted_src[k];                 // wave-uniform broadcast
            float e = al_s[s] + ald;
            e = (e > 0.f) ? e : LR_ATT * e;
            float ex = __expf(e - m);
            float hv = h[(size_t)s * HID + lane];  // coalesced 256B gather
            acc = fmaf(ex, hv, acc);
            sum += ex;
        }

        float v = acc / sum + bc;
        v = (v > 0.f) ? v : LR_ACT * v;
        if (!FUSE_HEAD) {
            hout[(size_t)d * HID + lane] = v;
        } else {
            v *= wc;
            #pragma unroll
            for (int off = 32; off; off >>= 1) v += __shfl_xor(v, off);
            if (lane == 0) out[d] = v + bout[0];
        }
    }
}

extern "C" void kernel_launch(void* const* d_in, const int* in_sizes, int n_in,
                              void* d_out, int out_size, void* d_ws, size_t ws_size,
                              hipStream_t stream)
{
    const float* x      = (const float*)d_in[0];
    const int*   ei     = (const int*)  d_in[1];
    const float* W1     = (const float*)d_in[2];
    const float* a_src1 = (const float*)d_in[3];
    const float* a_dst1 = (const float*)d_in[4];
    const float* b1     = (const float*)d_in[5];
    const float* W2     = (const float*)d_in[6];
    const float* a_src2 = (const float*)d_in[7];
    const float* a_dst2 = (const float*)d_in[8];
    const float* b2     = (const float*)d_in[9];
    const float* W3     = (const float*)d_in[10];
    const float* a_src3 = (const float*)d_in[11];
    const float* a_dst3 = (const float*)d_in[12];
    const float* b3     = (const float*)d_in[13];
    const float* W_out  = (const float*)d_in[14];
    const float* b_out  = (const float*)d_in[15];
    float* out = (float*)d_out;

    const int n = out_size;           // 50000 nodes
    const int E = in_sizes[1] / 2;    // 1.6M edges

    const int* src = ei;
    const int* dst = ei + E;

    // workspace layout
    float* ws   = (float*)d_ws;
    float* hA   = ws;                        // n*64
    float* hB   = hA + (size_t)n * HID;      // n*64
    float* al_s = hB + (size_t)n * HID;      // n
    float* al_d = al_s + n;                  // n
    int* counts     = (int*)(al_d + n);      // n
    int* offsets    = counts + n;            // n+1
    int* cursor     = offsets + (n + 1);     // n
    int* sorted_src = cursor + n;            // E

    dim3 blk(256);
    const int gemm_grid = 1024;
    const int edge_grid = 4096;
    const int node_grid = (n + 3) / 4;       // 4 waves/block, 1 wave/node

    // ---- CSR build (graph is layer-invariant) ----
    hipMemsetAsync(counts, 0, (size_t)n * sizeof(int), stream);
    count_kernel<<<edge_grid, blk, 0, stream>>>(dst, counts, E);
    scan_kernel<<<1, SCAN_NT, 0, stream>>>(counts, offsets, cursor, n);
    scatter_kernel<<<edge_grid, blk, 0, stream>>>(src, dst, cursor, sorted_src, E);

    // ---- layer 1 (K = 128) ----
    gemm_att_kernel<128><<<gemm_grid, blk, 0, stream>>>(x, W1, a_src1, a_dst1,
        hA, al_s, al_d, n);
    node_agg_kernel<false><<<node_grid, blk, 0, stream>>>(offsets, sorted_src,
        al_s, al_d, hA, b1, hB, nullptr, nullptr, nullptr, n);

    // ---- layer 2 (K = 64) ----
    gemm_att_kernel<64><<<gemm_grid, blk, 0, stream>>>(hB, W2, a_src2, a_dst2,
        hA, al_s, al_d, n);
    node_agg_kernel<false><<<node_grid, blk, 0, stream>>>(offsets, sorted_src,
        al_s, al_d, hA, b2, hB, nullptr, nullptr, nullptr, n);

    // ---- layer 3 (K = 64) + fused output head ----
    gemm_att_kernel<64><<<gemm_grid, blk, 0, stream>>>(hB, W3, a_src3, a_dst3,
        hA, al_s, al_d, n);
    node_agg_kernel<true><<<node_grid, blk, 0, stream>>>(offsets, sorted_src,
        al_s, al_d, hA, b3, nullptr, W_out, b_out, out, n);
}

// Round 10
// 657.579 us; speedup vs baseline: 2.6348x; 1.0029x over previous
//
#include <hip/hip_runtime.h>
#include <math.h>

#define HID 64
#define LR_ATT 0.2f
#define LR_ACT 0.01f
#define SCAN_NT 1024

// ---------------- CSR build (once per call; graph shared by all 3 layers) ----------------

__global__ __launch_bounds__(256) void count_kernel(
    const int* __restrict__ dst, int* __restrict__ counts, int E)
{
    int i = blockIdx.x * blockDim.x + threadIdx.x;
    int stride = gridDim.x * blockDim.x;
    for (; i < E; i += stride) atomicAdd(&counts[dst[i]], 1);
}

// Single-block exclusive scan of counts[0..n) -> offsets[0..n], plus cursor copy.
__global__ __launch_bounds__(SCAN_NT) void scan_kernel(
    const int* __restrict__ counts, int* __restrict__ offsets,
    int* __restrict__ cursor, int n)
{
    __shared__ int sdata[SCAN_NT];
    const int t = threadIdx.x;
    const int C = (n + SCAN_NT - 1) / SCAN_NT;
    const int beg = t * C;
    const int end = min(n, beg + C);

    int local = 0;
    for (int i = beg; i < end; ++i) local += counts[i];
    sdata[t] = local;
    __syncthreads();
    // Hillis-Steele inclusive scan
    for (int off = 1; off < SCAN_NT; off <<= 1) {
        int v = (t >= off) ? sdata[t - off] : 0;
        __syncthreads();
        sdata[t] += v;
        __syncthreads();
    }
    int run = sdata[t] - local;  // exclusive base for this thread's chunk
    for (int i = beg; i < end; ++i) {
        offsets[i] = run;
        cursor[i]  = run;
        run += counts[i];
    }
    if (end == n && beg <= n) offsets[n] = run;  // total == E
}

__global__ __launch_bounds__(256) void scatter_kernel(
    const int* __restrict__ src, const int* __restrict__ dst,
    int* __restrict__ cursor, int* __restrict__ sorted_src, int E)
{
    int i = blockIdx.x * blockDim.x + threadIdx.x;
    int stride = gridDim.x * blockDim.x;
    for (; i < E; i += stride) {
        int d = dst[i];
        int pos = atomicAdd(&cursor[d], 1);
        sorted_src[pos] = src[i];
    }
}

// ---------------- per-layer kernels ----------------

// h = hin @ W  (K x 64), al_s = h.a_src, al_d = h.a_dst.
// One wave per node (grid-stride). Lane c owns output channel c.
// W column held in registers (K VGPRs); input row broadcast via __shfl.
template<int K>
__global__ __launch_bounds__(256) void gemm_att_kernel(
    const float* __restrict__ hin, const float* __restrict__ W,
    const float* __restrict__ a_src, const float* __restrict__ a_dst,
    float* __restrict__ hout, float* __restrict__ al_s, float* __restrict__ al_d,
    int n_nodes)
{
    const int lane = threadIdx.x & 63;
    const int wib  = threadIdx.x >> 6;
    const int wpb  = blockDim.x >> 6;
    int wid = blockIdx.x * wpb + wib;
    int nw  = gridDim.x * wpb;

    float wreg[K];
    #pragma unroll
    for (int k = 0; k < K; ++k) wreg[k] = W[k * HID + lane];

    const float as = a_src[lane];
    const float ad = a_dst[lane];

    for (int nn = wid; nn < n_nodes; nn += nw) {
        const float* xr = hin + (size_t)nn * K;
        float r[K / 64];
        #pragma unroll
        for (int j = 0; j < K / 64; ++j) r[j] = xr[j * 64 + lane];

        float acc = 0.f;
        #pragma unroll
        for (int k = 0; k < K; ++k)
            acc = fmaf(__shfl(r[k >> 6], k & 63), wreg[k], acc);

        hout[(size_t)nn * HID + lane] = acc;

        float ps = acc * as, pd = acc * ad;
        #pragma unroll
        for (int off = 32; off; off >>= 1) {
            ps += __shfl_xor(ps, off);
            pd += __shfl_xor(pd, off);
        }
        if (lane == 0) {
            al_s[nn] = ps;
            al_d[nn] = pd;
        }
    }
}

// One wave per dst node. Phase 1: lane-parallel segment max.
// Phase 2: TWO edges per wave (half-wave per edge), float2 channel pair per
// lane -> one 512B dwordx2 gather instruction covers 2 edges. Halves combined
// with one shfl_xor(32). Fused divide+bias+leaky_relu (+optional head).
template<bool FUSE_HEAD>
__global__ __launch_bounds__(256) void node_agg_kernel(
    const int* __restrict__ offsets, const int* __restrict__ sorted_src,
    const float* __restrict__ al_s, const float* __restrict__ al_d,
    const float* __restrict__ h, const float* __restrict__ b,
    float* __restrict__ hout,
    const float* __restrict__ Wout, const float* __restrict__ bout,
    float* __restrict__ out, int n_nodes)
{
    const int lane = threadIdx.x & 63;
    const int half = lane >> 5;        // which edge of the pair
    const int ch   = (lane & 31) * 2;  // channel pair owned by this lane
    const int wib  = threadIdx.x >> 6;
    const int wpb  = blockDim.x >> 6;
    int wid = blockIdx.x * wpb + wib;
    int nw  = gridDim.x * wpb;

    const float2 bc = *(const float2*)&b[ch];
    const float2 wc = FUSE_HEAD ? *(const float2*)&Wout[ch] : float2{0.f, 0.f};

    for (int d = wid; d < n_nodes; d += nw) {
        const float ald = al_d[d];
        float e0 = al_s[d] + ald;           // self-loop logit
        e0 = (e0 > 0.f) ? e0 : LR_ATT * e0;

        const int k0 = offsets[d];
        const int k1 = offsets[d + 1];

        // ---- phase 1: full-wave lane-parallel max ----
        float lm = e0;
        for (int k = k0 + lane; k < k1; k += 64) {
            int s = sorted_src[k];
            float e = al_s[s] + ald;
            e = (e > 0.f) ? e : LR_ATT * e;
            lm = fmaxf(lm, e);
        }
        #pragma unroll
        for (int off = 32; off; off >>= 1)
            lm = fmaxf(lm, __shfl_xor(lm, off));
        const float m = lm;

        // ---- phase 2: 2 edges/iteration, branch-free ----
        float ex0 = (half == 0) ? __expf(e0 - m) : 0.f;  // self-loop in half 0
        float sum = ex0;
        const float2 hd = *(const float2*)&h[(size_t)d * HID + ch];
        float2 acc;
        acc.x = ex0 * hd.x;
        acc.y = ex0 * hd.y;

        int k = k0;
        #pragma unroll 4
        for (; k + 1 < k1; k += 2) {
            int s = sorted_src[k + half];              // uniform per half-wave
            float e = al_s[s] + ald;
            e = (e > 0.f) ? e : LR_ATT * e;
            float ex = __expf(e - m);
            float2 hv = *(const float2*)&h[(size_t)s * HID + ch];
            acc.x = fmaf(ex, hv.x, acc.x);
            acc.y = fmaf(ex, hv.y, acc.y);
            sum += ex;
        }
        if (k < k1) {                                  // odd tail edge
            int s = sorted_src[k];
            float e = al_s[s] + ald;
            e = (e > 0.f) ? e : LR_ATT * e;
            float ex = (half == 0) ? __expf(e - m) : 0.f;
            float2 hv = *(const float2*)&h[(size_t)s * HID + ch];
            acc.x = fmaf(ex, hv.x, acc.x);
            acc.y = fmaf(ex, hv.y, acc.y);
            sum += ex;
        }

        // ---- combine the two halves ----
        acc.x += __shfl_xor(acc.x, 32);
        acc.y += __shfl_xor(acc.y, 32);
        sum   += __shfl_xor(sum, 32);

        float2 v;
        v.x = acc.x / sum + bc.x;
        v.y = acc.y / sum + bc.y;
        v.x = (v.x > 0.f) ? v.x : LR_ACT * v.x;
        v.y = (v.y > 0.f) ? v.y : LR_ACT * v.y;

        if (!FUSE_HEAD) {
            if (lane < 32) *(float2*)&hout[(size_t)d * HID + ch] = v;
        } else {
            float t = v.x * wc.x + v.y * wc.y;
            #pragma unroll
            for (int off = 16; off; off >>= 1) t += __shfl_xor(t, off);
            if (lane == 0) out[d] = t + bout[0];
        }
    }
}

extern "C" void kernel_launch(void* const* d_in, const int* in_sizes, int n_in,
                              void* d_out, int out_size, void* d_ws, size_t ws_size,
                              hipStream_t stream)
{
    const float* x      = (const float*)d_in[0];
    const int*   ei     = (const int*)  d_in[1];
    const float* W1     = (const float*)d_in[2];
    const float* a_src1 = (const float*)d_in[3];
    const float* a_dst1 = (const float*)d_in[4];
    const float* b1     = (const float*)d_in[5];
    const float* W2     = (const float*)d_in[6];
    const float* a_src2 = (const float*)d_in[7];
    const float* a_dst2 = (const float*)d_in[8];
    const float* b2     = (const float*)d_in[9];
    const float* W3     = (const float*)d_in[10];
    const float* a_src3 = (const float*)d_in[11];
    const float* a_dst3 = (const float*)d_in[12];
    const float* b3     = (const float*)d_in[13];
    const float* W_out  = (const float*)d_in[14];
    const float* b_out  = (const float*)d_in[15];
    float* out = (float*)d_out;

    const int n = out_size;           // 50000 nodes
    const int E = in_sizes[1] / 2;    // 1.6M edges

    const int* src = ei;
    const int* dst = ei + E;

    // workspace layout
    float* ws   = (float*)d_ws;
    float* hA   = ws;                        // n*64
    float* hB   = hA + (size_t)n * HID;      // n*64
    float* al_s = hB + (size_t)n * HID;      // n
    float* al_d = al_s + n;                  // n
    int* counts     = (int*)(al_d + n);      // n
    int* offsets    = counts + n;            // n+1
    int* cursor     = offsets + (n + 1);     // n
    int* sorted_src = cursor + n;            // E

    dim3 blk(256);
    const int gemm_grid = 1024;
    const int edge_grid = 4096;
    const int node_grid = (n + 3) / 4;       // 4 waves/block, 1 wave/node

    // ---- CSR build (graph is layer-invariant) ----
    hipMemsetAsync(counts, 0, (size_t)n * sizeof(int), stream);
    count_kernel<<<edge_grid, blk, 0, stream>>>(dst, counts, E);
    scan_kernel<<<1, SCAN_NT, 0, stream>>>(counts, offsets, cursor, n);
    scatter_kernel<<<edge_grid, blk, 0, stream>>>(src, dst, cursor, sorted_src, E);

    // ---- layer 1 (K = 128) ----
    gemm_att_kernel<128><<<gemm_grid, blk, 0, stream>>>(x, W1, a_src1, a_dst1,
        hA, al_s, al_d, n);
    node_agg_kernel<false><<<node_grid, blk, 0, stream>>>(offsets, sorted_src,
        al_s, al_d, hA, b1, hB, nullptr, nullptr, nullptr, n);

    // ---- layer 2 (K = 64) ----
    gemm_att_kernel<64><<<gemm_grid, blk, 0, stream>>>(hB, W2, a_src2, a_dst2,
        hA, al_s, al_d, n);
    node_agg_kernel<false><<<node_grid, blk, 0, stream>>>(offsets, sorted_src,
        al_s, al_d, hA, b2, hB, nullptr, nullptr, nullptr, n);

    // ---- layer 3 (K = 64) + fused output head ----
    gemm_att_kernel<64><<<gemm_grid, blk, 0, stream>>>(hB, W3, a_src3, a_dst3,
        hA, al_s, al_d, n);
    node_agg_kernel<true><<<node_grid, blk, 0, stream>>>(offsets, sorted_src,
        al_s, al_d, hA, b3, nullptr, W_out, b_out, out, n);
}